// Round 14
// baseline (309.422 us; speedup 1.0000x reference)
//
#include <hip/hip_runtime.h>

typedef _Float16 f16x8 __attribute__((ext_vector_type(8)));
typedef _Float16 f16x4 __attribute__((ext_vector_type(4)));
typedef float    f32x4 __attribute__((ext_vector_type(4)));
typedef float    f32x16 __attribute__((ext_vector_type(16)));

#define B_N    4
#define L_TOT  4096
#define H_N    16
#define DH     64
#define HALF_D 32
#define QT     64
#define KT     64
#define LDSP   72          // fallback kernel pad

#define LOG2_BASE 13.287712379549449f   // log2(10000)
#define LOG2E     1.4426950408889634f

#define TAB_BYTES  ((size_t)L_TOT * 64 * sizeof(float))          // 1 MB
#define IMG_BYTES  ((size_t)B_N * H_N * 64 * 8192)               // 32 MB per image

// ---------------- RoPE cos/sin table: tab[l][0..31]=cos, [32..63]=sin ----------------
__global__ void rope_table_kernel(const int* __restrict__ sidx, float* __restrict__ tab) {
    int idx = blockIdx.x * 256 + (int)threadIdx.x;
    if (idx >= L_TOT * HALF_D) return;
    int l = idx >> 5;
    int j = idx & 31;
    float invf = exp2f(-(float)j * (LOG2_BASE / (float)HALF_D));
    float ang = (float)(sidx[0] + l) * invf;
    float s, c;
    sincosf(ang, &s, &c);
    tab[l * 64 + j] = c;
    tab[l * 64 + HALF_D + j] = s;
}

// ---------------- fused prep: K (RoPE'd) + V^T, both XOR-swizzled f16 image tiles ----------------
// tile: [row 0..63][chunk 0..7 of 16B], stored chunk' = chunk ^ (row&7)  (validated rounds 7/10/12)
__global__ __launch_bounds__(256)
void prep_kernel(const float* __restrict__ k, const float* __restrict__ v,
                 const float* __restrict__ tab,
                 unsigned char* __restrict__ kimg, unsigned char* __restrict__ vimg)
{
    __shared__ float Vs[64][65];
    int bid = (int)blockIdx.x;
    int t = (int)threadIdx.x;

    if (bid < 4096) {
        int task = bid * 256 + t;              // B*H*L*4 tasks
        int c = task & 3;
        int rowid = task >> 2;
        int l = rowid & (L_TOT - 1);
        int bh = rowid >> 12;
        int b = bh >> 4, h = bh & 15;
        int d0 = c * 8;                        // 0,8,16,24
        const float* src = k + (((size_t)b * L_TOT + l) * H_N + h) * (size_t)DH;
        f32x4 x1a = *(const f32x4*)(src + d0);
        f32x4 x1b = *(const f32x4*)(src + d0 + 4);
        f32x4 x2a = *(const f32x4*)(src + d0 + HALF_D);
        f32x4 x2b = *(const f32x4*)(src + d0 + HALF_D + 4);
        const float* tr = tab + (size_t)l * 64 + d0;
        f32x4 ca = *(const f32x4*)(tr);
        f32x4 cb = *(const f32x4*)(tr + 4);
        f32x4 sa = *(const f32x4*)(tr + HALF_D);
        f32x4 sb = *(const f32x4*)(tr + HALF_D + 4);
        f16x8 olo, ohi;
#pragma unroll
        for (int j = 0; j < 4; ++j) {
            olo[j]     = (_Float16)(x1a[j] * ca[j] - x2a[j] * sa[j]);
            olo[j + 4] = (_Float16)(x1b[j] * cb[j] - x2b[j] * sb[j]);
            ohi[j]     = (_Float16)(x1a[j] * sa[j] + x2a[j] * ca[j]);
            ohi[j + 4] = (_Float16)(x1b[j] * sb[j] + x2b[j] * cb[j]);
        }
        size_t tile = (size_t)bh * 64 + (l >> 6);
        unsigned char* dst = kimg + tile * 8192 + (size_t)(l & 63) * 128;
        int sw = (c ^ (l & 7)) << 4;
        *(f16x8*)(dst + sw)        = olo;      // chunk c   (d = 8c..8c+7)
        *(f16x8*)(dst + (sw ^ 64)) = ohi;      // chunk c+4 (d+32)
    } else {
        int vb = bid - 4096;                   // b*H*64 + h*64 + tile
        int tile = vb & 63;
        int h = (vb >> 6) & 15;
        int b = vb >> 10;
        int kbase = tile * 64;
        int row = t >> 2, cb = t & 3;
        const float* src = v + (((size_t)b * L_TOT + kbase + row) * H_N + h) * (size_t)DH + cb * 16;
        f32x4 a0 = *(const f32x4*)(src);
        f32x4 a1 = *(const f32x4*)(src + 4);
        f32x4 a2 = *(const f32x4*)(src + 8);
        f32x4 a3 = *(const f32x4*)(src + 12);
#pragma unroll
        for (int j = 0; j < 4; ++j) {
            Vs[row][cb * 16 + j]      = a0[j];
            Vs[row][cb * 16 + 4 + j]  = a1[j];
            Vs[row][cb * 16 + 8 + j]  = a2[j];
            Vs[row][cb * 16 + 12 + j] = a3[j];
        }
        __syncthreads();
        size_t tbase = ((size_t)(b * 16 + h) * 64 + tile) * 8192;
#pragma unroll
        for (int e = 0; e < 2; ++e) {
            int task = e * 256 + t;            // dv x chunk
            int dv = task >> 3, c = task & 7;
            f16x8 o;
#pragma unroll
            for (int j = 0; j < 8; ++j) o[j] = (_Float16)Vs[8 * c + j][dv];
            *(f16x8*)(vimg + tbase + (size_t)dv * 128 + ((c ^ (dv & 7)) << 4)) = o;
        }
    }
}

__device__ __forceinline__ unsigned pku(float a, float b) {
    return __builtin_bit_cast(unsigned, __builtin_amdgcn_cvt_pkrtz(a, b));
}

// ---------------- main: 32x32x16 MFMA, round-12 geometry + T14 reg-staged single buffer ----------------
// 2 waves x 32 q-rows = 64 q/block, one head, one qtile (validated geometry). LDS: single
// K 8K + V 8K = 16 KB -> up to 8-10 blocks/CU. Staging: tile kb+1 global->regs at iteration
// top (latency hides under compute), regs->LDS between two barriers. All branches block-uniform.
__global__ __launch_bounds__(128, 4)
void attn_main_kernel(const float* __restrict__ q, const int* __restrict__ csz,
                      const float* __restrict__ tab,
                      const unsigned char* __restrict__ kimg,
                      const unsigned char* __restrict__ vimg,
                      float* __restrict__ out) {
    __shared__ __align__(16) unsigned char smem[16384];   // [K 8K | V 8K], single-buffered

    const int tid  = (int)threadIdx.x;
    const int lane = tid & 63;
    const int w    = tid >> 6;         // wave 0..1, owns q rows [32w, 32w+32)
    const int qi   = lane & 31;        // q within wave
    const int h    = lane >> 5;        // k/d half selector
    const int e7   = lane & 7;

    // XCD swizzle (bijective, 4096 % 8 == 0) -- round-7/12 exact
    const int bid0  = (int)blockIdx.x;
    const int wg    = (bid0 & 7) * 512 + (bid0 >> 3);
    const int qx    = wg & 63;
    const int hh    = (wg >> 6) & 15;
    const int b     = wg >> 10;

    const int C   = csz[0];
    const int tpc = C >> 6;
    const int qtile = qx ^ ((tpc - 1) & 63);     // heavy-first within chunk (round-7 exact)
    const int kb0 = (qtile / tpc) * tpc;

    const int qg = qtile * QT + 32 * w + qi;     // global q row
    const int qloc = 32 * w + qi;                // row within the 64-tile

    // ---- Q B-fragments (32x32x16): lane holds Q[q=qg][d = 16s + 8h + j], RoPE'd, LOG2E folded ----
    const float* qs = q + (((size_t)b * L_TOT + qg) * H_N + hh) * (size_t)DH;
    const int d0 = 8 * h;
    f32x4 xa0 = *(const f32x4*)(qs + d0);       f32x4 xa1 = *(const f32x4*)(qs + d0 + 4);
    f32x4 xb0 = *(const f32x4*)(qs + d0 + 16);  f32x4 xb1 = *(const f32x4*)(qs + d0 + 20);
    f32x4 xc0 = *(const f32x4*)(qs + d0 + 32);  f32x4 xc1 = *(const f32x4*)(qs + d0 + 36);
    f32x4 xd0 = *(const f32x4*)(qs + d0 + 48);  f32x4 xd1 = *(const f32x4*)(qs + d0 + 52);
    const float* tr = tab + (size_t)qg * 64;
    f32x4 ca0 = *(const f32x4*)(tr + d0);       f32x4 ca1 = *(const f32x4*)(tr + d0 + 4);
    f32x4 cb0 = *(const f32x4*)(tr + d0 + 16);  f32x4 cb1 = *(const f32x4*)(tr + d0 + 20);
    f32x4 sa0 = *(const f32x4*)(tr + 32 + d0);      f32x4 sa1 = *(const f32x4*)(tr + 32 + d0 + 4);
    f32x4 sb0 = *(const f32x4*)(tr + 32 + d0 + 16); f32x4 sb1 = *(const f32x4*)(tr + 32 + d0 + 20);
    f16x8 qf0, qf1, qf2, qf3;
#pragma unroll
    for (int j = 0; j < 4; ++j) {
        qf0[j]     = (_Float16)((xa0[j] * ca0[j] - xc0[j] * sa0[j]) * LOG2E);
        qf0[j + 4] = (_Float16)((xa1[j] * ca1[j] - xc1[j] * sa1[j]) * LOG2E);
        qf1[j]     = (_Float16)((xb0[j] * cb0[j] - xd0[j] * sb0[j]) * LOG2E);
        qf1[j + 4] = (_Float16)((xb1[j] * cb1[j] - xd1[j] * sb1[j]) * LOG2E);
        qf2[j]     = (_Float16)((xa0[j] * sa0[j] + xc0[j] * ca0[j]) * LOG2E);
        qf2[j + 4] = (_Float16)((xa1[j] * sa1[j] + xc1[j] * ca1[j]) * LOG2E);
        qf3[j]     = (_Float16)((xb0[j] * sb0[j] + xd0[j] * cb0[j]) * LOG2E);
        qf3[j + 4] = (_Float16)((xb1[j] * sb1[j] + xd1[j] * cb1[j]) * LOG2E);
    }

    const unsigned char* ksrc = kimg + (size_t)(b * 16 + hh) * 64 * 8192;
    const unsigned char* vsrc = vimg + (size_t)(b * 16 + hh) * 64 * 8192;

    // A-frag read base: image row qi (rows 32..63 via +4096), chunk (h + 2s) ^ e7
    const int rbase = qi * 128;
    const char* Kb = (const char*)smem;
    const char* Vb = (const char*)(smem + 8192);

    // accumulators: O^T blocks (dv 0..31 / 32..63), softmax state in log2 domain
    f32x16 acc0 = {}, acc1 = {};
    float m = -3e38f, l = 0.f;

    // ---- prologue: stage tile kb0 via registers (coalesced: lane-contiguous 16B per step) ----
    uint4 stg[8];
    {
        const unsigned char* gk = ksrc + (size_t)kb0 * 8192;
        const unsigned char* gv = vsrc + (size_t)kb0 * 8192;
#pragma unroll
        for (int e = 0; e < 4; ++e) {
            stg[e]     = *(const uint4*)(gk + tid * 16 + e * 2048);
            stg[e + 4] = *(const uint4*)(gv + tid * 16 + e * 2048);
        }
#pragma unroll
        for (int e = 0; e < 4; ++e) {
            *(uint4*)(smem + tid * 16 + e * 2048)        = stg[e];
            *(uint4*)(smem + 8192 + tid * 16 + e * 2048) = stg[e + 4];
        }
    }
    __syncthreads();

    for (int kb = kb0; kb <= qtile; ++kb) {
        const bool more = (kb < qtile);          // block-uniform
        // ---- T14 issue-early: next tile global->regs; latency hides under this tile's compute ----
        if (more) {
            const unsigned char* gk = ksrc + (size_t)(kb + 1) * 8192;
            const unsigned char* gv = vsrc + (size_t)(kb + 1) * 8192;
#pragma unroll
            for (int e = 0; e < 4; ++e) {
                stg[e]     = *(const uint4*)(gk + tid * 16 + e * 2048);
                stg[e + 4] = *(const uint4*)(gv + tid * 16 + e * 2048);
            }
        }

        // ---- swapped QK^T (32x32x16): sc{0,1}[r] = S[k_loc = {0,32} + (r&3)+8*(r>>2)+4h][q=qg] ----
        f32x16 sc0 = {}, sc1 = {};
        __builtin_amdgcn_s_setprio(1);
#pragma unroll
        for (int s = 0; s < 4; ++s) {
            f16x8 kf = *(const f16x8*)(Kb + rbase + (((h + 2 * s) ^ e7) << 4));
            const f16x8 qv = (s == 0) ? qf0 : (s == 1) ? qf1 : (s == 2) ? qf2 : qf3;
            sc0 = __builtin_amdgcn_mfma_f32_32x32x16_f16(kf, qv, sc0, 0, 0, 0);
        }
#pragma unroll
        for (int s = 0; s < 4; ++s) {
            f16x8 kf = *(const f16x8*)(Kb + 4096 + rbase + (((h + 2 * s) ^ e7) << 4));
            const f16x8 qv = (s == 0) ? qf0 : (s == 1) ? qf1 : (s == 2) ? qf2 : qf3;
            sc1 = __builtin_amdgcn_mfma_f32_32x32x16_f16(kf, qv, sc1, 0, 0, 0);
        }
        __builtin_amdgcn_s_setprio(0);

        // ---- causal mask on the diagonal tile (block-uniform branch) ----
        if (kb == qtile) {
#pragma unroll
            for (int r = 0; r < 16; ++r) {
                const int kl = (r & 3) + 8 * (r >> 2) + 4 * h;
                if (kl > qloc)      sc0[r] = -3e38f;
                if (kl + 32 > qloc) sc1[r] = -3e38f;
            }
        }

        // ---- online softmax (log2 domain), defer-max; q fully lane-local + one cross-half shfl ----
        float m0 = sc0[0], m1 = sc0[1], m2 = sc0[2], m3 = sc0[3];
#pragma unroll
        for (int r = 4; r < 16; r += 4) {
            m0 = fmaxf(m0, sc0[r]);     m1 = fmaxf(m1, sc0[r + 1]);
            m2 = fmaxf(m2, sc0[r + 2]); m3 = fmaxf(m3, sc0[r + 3]);
        }
#pragma unroll
        for (int r = 0; r < 16; r += 4) {
            m0 = fmaxf(m0, sc1[r]);     m1 = fmaxf(m1, sc1[r + 1]);
            m2 = fmaxf(m2, sc1[r + 2]); m3 = fmaxf(m3, sc1[r + 3]);
        }
        float mx = fmaxf(fmaxf(m0, m1), fmaxf(m2, m3));
        mx = fmaxf(mx, __shfl_xor(mx, 32));
        if (__any(mx - m > 8.0f)) {
            float mn  = fmaxf(m, mx);
            float scl = exp2f(m - mn);
            m = mn;
            l *= scl;
#pragma unroll
            for (int r = 0; r < 16; ++r) { acc0[r] *= scl; acc1[r] *= scl; }
        }
        // exponentiate into SEPARATE packed registers (round-10/12-validated dataflow)
        unsigned pkA[8], pkB[8];
        float s0 = 0.f, s1 = 0.f, s2 = 0.f, s3 = 0.f;
#pragma unroll
        for (int i = 0; i < 8; ++i) {
            float a0 = exp2f(sc0[2 * i] - m);
            float a1 = exp2f(sc0[2 * i + 1] - m);
            s0 += a0; s1 += a1;
            pkA[i] = pku(a0, a1);
            float b0 = exp2f(sc1[2 * i] - m);
            float b1 = exp2f(sc1[2 * i + 1] - m);
            s2 += b0; s3 += b1;
            pkB[i] = pku(b0, b1);
        }
        float ps = (s0 + s1) + (s2 + s3);
        ps += __shfl_xor(ps, 32);
        l += ps;

        // ---- PV (32x32x16): P B-frags via 2 shfl_xor(32) per ks; V^T from LDS ----
        __builtin_amdgcn_s_setprio(1);
#pragma unroll
        for (int ks = 0; ks < 4; ++ks) {
            const int base = 4 * (ks & 1);
            unsigned w0, w1, w2, w3;
            if (ks < 2) {
                w0 = pkA[base];     w1 = pkA[base + 1];
                w2 = pkA[base + 2]; w3 = pkA[base + 3];
            } else {
                w0 = pkB[base];     w1 = pkB[base + 1];
                w2 = pkB[base + 2]; w3 = pkB[base + 3];
            }
            unsigned x = h ? w0 : w2;
            unsigned y = h ? w1 : w3;
            unsigned xs = (unsigned)__shfl_xor((int)x, 32);
            unsigned ys = (unsigned)__shfl_xor((int)y, 32);
            uint4 fw;
            fw.x = h ? xs : w0;
            fw.y = h ? ys : w1;
            fw.z = h ? w2 : xs;
            fw.w = h ? w3 : ys;
            f16x8 pbf = __builtin_bit_cast(f16x8, fw);
            const int voff = ((h + 2 * ks) ^ e7) << 4;
            f16x8 v0 = *(const f16x8*)(Vb + rbase + voff);
            f16x8 v1 = *(const f16x8*)(Vb + 4096 + rbase + voff);
            acc0 = __builtin_amdgcn_mfma_f32_32x32x16_f16(v0, pbf, acc0, 0, 0, 0);
            acc1 = __builtin_amdgcn_mfma_f32_32x32x16_f16(v1, pbf, acc1, 0, 0, 0);
        }
        __builtin_amdgcn_s_setprio(0);

        // ---- T14 write-late: all waves done reading tile kb, then regs->LDS, then visible ----
        __syncthreads();
        if (more) {
#pragma unroll
            for (int e = 0; e < 4; ++e) {
                *(uint4*)(smem + tid * 16 + e * 2048)        = stg[e];
                *(uint4*)(smem + 8192 + tid * 16 + e * 2048) = stg[e + 4];
            }
        }
        __syncthreads();
    }

    // ---- epilogue: direct global stores (C/D map: dv = (r&3)+8*(r>>2)+4h, q = qi) ----
    float inv = 1.f / l;
    float* orow = out + (((size_t)b * L_TOT + qg) * H_N + hh) * (size_t)DH;
#pragma unroll
    for (int t = 0; t < 4; ++t) {
        f32x4 v0, v1;
#pragma unroll
        for (int u = 0; u < 4; ++u) {
            v0[u] = acc0[4 * t + u] * inv;
            v1[u] = acc1[4 * t + u] * inv;
        }
        *(f32x4*)(orow + 8 * t + 4 * h)      = v0;   // dv = 8t + 4h + u
        *(f32x4*)(orow + 32 + 8 * t + 4 * h) = v1;   // dv = 32 + 8t + 4h + u
    }
}

// ================= fallback (round-2 kernel, unchanged) =================
__device__ __forceinline__ void rope_cs_inline(float pos, int d, float* cc, float* ss) {
    float invf = exp2f(-(float)d * (LOG2_BASE / (float)HALF_D));
    float s, c;
    sincosf(pos * invf, &s, &c);
    *cc = c;
    *ss = s;
}

template<bool TAB>
__global__ __launch_bounds__(256)
void chunked_attn_kernel(const float* __restrict__ q, const float* __restrict__ k,
                         const float* __restrict__ v, const int* __restrict__ csz,
                         const int* __restrict__ sidx, const float* __restrict__ tab,
                         float* __restrict__ out)
{
    __shared__ _Float16 Ks[KT][LDSP];
    __shared__ _Float16 Vt[DH][LDSP];
    __shared__ _Float16 Ps[4][16][LDSP];

    const int tid  = (int)threadIdx.x;
    const int lane = tid & 63;
    const int w    = tid >> 6;
    const int cl   = lane & 15;
    const int g    = lane >> 4;

    const int bid   = (int)blockIdx.x;
    const int qtile = bid & (L_TOT / QT - 1);
    const int h     = (bid >> 6) & (H_N - 1);
    const int b     = bid >> 10;

    const int C   = csz[0];
    const int S0  = sidx[0];
    const int tpc = C / KT;
    const int kb0 = (qtile / tpc) * tpc;

    const int qrow = qtile * QT + w * 16 + cl;
    const size_t qoff = (((size_t)b * L_TOT + qrow) * H_N + h) * (size_t)DH;
    f32x4 x1a = *(const f32x4*)(q + qoff + 8 * g);
    f32x4 x1b = *(const f32x4*)(q + qoff + 8 * g + 4);
    f32x4 x2a = *(const f32x4*)(q + qoff + 8 * g + HALF_D);
    f32x4 x2b = *(const f32x4*)(q + qoff + 8 * g + HALF_D + 4);
    f32x4 ca, cb, sa, sb;
    if (TAB) {
        const float* tr = tab + (size_t)qrow * 64 + 8 * g;
        ca = *(const f32x4*)(tr);
        cb = *(const f32x4*)(tr + 4);
        sa = *(const f32x4*)(tr + HALF_D);
        sb = *(const f32x4*)(tr + HALF_D + 4);
    } else {
        float pos = (float)(S0 + qrow);
#pragma unroll
        for (int j = 0; j < 4; ++j) {
            float c0, s0, c1, s1;
            rope_cs_inline(pos, 8 * g + j,     &c0, &s0);
            rope_cs_inline(pos, 8 * g + 4 + j, &c1, &s1);
            ca[j] = c0; sa[j] = s0;
            cb[j] = c1; sb[j] = s1;
        }
    }
    f16x8 qa0, qa1;
#pragma unroll
    for (int j = 0; j < 4; ++j) {
        qa0[j]     = (_Float16)(x1a[j] * ca[j] - x2a[j] * sa[j]);
        qa0[j + 4] = (_Float16)(x1b[j] * cb[j] - x2b[j] * sb[j]);
        qa1[j]     = (_Float16)(x1a[j] * sa[j] + x2a[j] * ca[j]);
        qa1[j + 4] = (_Float16)(x1b[j] * sb[j] + x2b[j] * cb[j]);
    }

    f32x4 o[4] = {};
    float m_r[4], l_r[4];
#pragma unroll
    for (int r = 0; r < 4; ++r) { m_r[r] = -3e38f; l_r[r] = 0.f; }

    for (int kb = kb0; kb <= qtile; ++kb) {
        __syncthreads();
        const int kbase = kb * KT;

#pragma unroll
        for (int e = 0; e < 2; ++e) {
            int task = e * 256 + tid;
            int kk = task >> 3;
            int dg = (task & 7) * 4;
            int grow = kbase + kk;
            size_t off = (((size_t)b * L_TOT + grow) * H_N + h) * (size_t)DH;
            f32x4 x1 = *(const f32x4*)(k + off + dg);
            f32x4 x2 = *(const f32x4*)(k + off + dg + HALF_D);
            f32x4 cc, ss;
            if (TAB) {
                const float* tr2 = tab + (size_t)grow * 64 + dg;
                cc = *(const f32x4*)(tr2);
                ss = *(const f32x4*)(tr2 + HALF_D);
            } else {
                float pos = (float)(S0 + grow);
#pragma unroll
                for (int j = 0; j < 4; ++j) {
                    float c0, s0;
                    rope_cs_inline(pos, dg + j, &c0, &s0);
                    cc[j] = c0; ss[j] = s0;
                }
            }
            f16x4 o1, o2;
#pragma unroll
            for (int j = 0; j < 4; ++j) {
                o1[j] = (_Float16)(x1[j] * cc[j] - x2[j] * ss[j]);
                o2[j] = (_Float16)(x1[j] * ss[j] + x2[j] * cc[j]);
            }
            *(f16x4*)&Ks[kk][dg]          = o1;
            *(f16x4*)&Ks[kk][dg + HALF_D] = o2;
        }

#pragma unroll
        for (int e = 0; e < 4; ++e) {
            int task = e * 256 + tid;
            int kk = task >> 4;
            int dq = (task & 15) * 4;
            int grow = kbase + kk;
            size_t off = (((size_t)b * L_TOT + grow) * H_N + h) * (size_t)DH + dq;
            f32x4 x = *(const f32x4*)(v + off);
#pragma unroll
            for (int i = 0; i < 4; ++i) Vt[dq + i][kk] = (_Float16)x[i];
        }
        __syncthreads();

        f32x4 sc[4];
#pragma unroll
        for (int ct = 0; ct < 4; ++ct) {
            f16x8 kf0 = *(const f16x8*)&Ks[ct * 16 + cl][8 * g];
            f16x8 kf1 = *(const f16x8*)&Ks[ct * 16 + cl][8 * g + HALF_D];
            f32x4 z = {};
            z = __builtin_amdgcn_mfma_f32_16x16x32_f16(qa0, kf0, z, 0, 0, 0);
            sc[ct] = __builtin_amdgcn_mfma_f32_16x16x32_f16(qa1, kf1, z, 0, 0, 0);
        }

        const int rowt = w * 16 + 4 * g;
        if (kb == qtile) {
#pragma unroll
            for (int ct = 0; ct < 4; ++ct)
#pragma unroll
                for (int r = 0; r < 4; ++r)
                    if (ct * 16 + cl > rowt + r) sc[ct][r] = -3e38f;
        }

        f32x4 mt;
#pragma unroll
        for (int r = 0; r < 4; ++r)
            mt[r] = fmaxf(fmaxf(sc[0][r], sc[1][r]), fmaxf(sc[2][r], sc[3][r]));
#pragma unroll
        for (int off = 1; off < 16; off <<= 1) {
#pragma unroll
            for (int r = 0; r < 4; ++r)
                mt[r] = fmaxf(mt[r], __shfl_xor(mt[r], off));
        }
        float scale_r[4];
#pragma unroll
        for (int r = 0; r < 4; ++r) {
            float mn = fmaxf(m_r[r], mt[r]);
            scale_r[r] = __expf(m_r[r] - mn);
            m_r[r] = mn;
        }
        f32x4 psum = {};
#pragma unroll
        for (int ct = 0; ct < 4; ++ct) {
#pragma unroll
            for (int r = 0; r < 4; ++r) {
                float pz = __expf(sc[ct][r] - m_r[r]);
                sc[ct][r] = pz;
                psum[r] += pz;
            }
        }
#pragma unroll
        for (int off = 1; off < 16; off <<= 1) {
#pragma unroll
            for (int r = 0; r < 4; ++r)
                psum[r] += __shfl_xor(psum[r], off);
        }
#pragma unroll
        for (int r = 0; r < 4; ++r) l_r[r] = l_r[r] * scale_r[r] + psum[r];
#pragma unroll
        for (int ct = 0; ct < 4; ++ct)
#pragma unroll
            for (int r = 0; r < 4; ++r) o[ct][r] *= scale_r[r];

#pragma unroll
        for (int ct = 0; ct < 4; ++ct)
#pragma unroll
            for (int r = 0; r < 4; ++r)
                Ps[w][4 * g + r][ct * 16 + cl] = (_Float16)sc[ct][r];

#pragma unroll
        for (int st = 0; st < 2; ++st) {
            f16x8 pa = *(const f16x8*)&Ps[w][cl][8 * g + 32 * st];
#pragma unroll
            for (int ct = 0; ct < 4; ++ct) {
                f16x8 vb = *(const f16x8*)&Vt[ct * 16 + cl][8 * g + 32 * st];
                o[ct] = __builtin_amdgcn_mfma_f32_16x16x32_f16(pa, vb, o[ct], 0, 0, 0);
            }
        }
    }

#pragma unroll
    for (int ct = 0; ct < 4; ++ct) {
#pragma unroll
        for (int r = 0; r < 4; ++r) {
            int row = qtile * QT + w * 16 + 4 * g + r;
            float val = o[ct][r] / l_r[r];
            out[(((size_t)b * L_TOT + row) * H_N + h) * (size_t)DH + ct * 16 + cl] = val;
        }
    }
}

extern "C" void kernel_launch(void* const* d_in, const int* in_sizes, int n_in,
                              void* d_out, int out_size, void* d_ws, size_t ws_size,
                              hipStream_t stream) {
    const float* q  = (const float*)d_in[0];
    const float* k  = (const float*)d_in[1];
    const float* v  = (const float*)d_in[2];
    const int* csz  = (const int*)d_in[3];
    const int* sidx = (const int*)d_in[4];
    float* out = (float*)d_out;

    const size_t TOTAL = TAB_BYTES + 2 * IMG_BYTES;   // ~66 MB
    const int grid = B_N * H_N * (L_TOT / QT);        // 4096

    if (ws_size >= TOTAL) {
        float* tab = (float*)d_ws;
        unsigned char* kimg = (unsigned char*)d_ws + TAB_BYTES;
        unsigned char* vimg = kimg + IMG_BYTES;
        rope_table_kernel<<<(L_TOT * HALF_D + 255) / 256, 256, 0, stream>>>(sidx, tab);
        prep_kernel<<<8192, 256, 0, stream>>>(k, v, tab, kimg, vimg);
        attn_main_kernel<<<grid, 128, 0, stream>>>(q, csz, tab, kimg, vimg, out);
    } else if (ws_size >= TAB_BYTES) {
        float* tab = (float*)d_ws;
        rope_table_kernel<<<(L_TOT * HALF_D + 255) / 256, 256, 0, stream>>>(sidx, tab);
        chunked_attn_kernel<true><<<grid, 256, 0, stream>>>(q, k, v, csz, sidx, tab, out);
    } else {
        chunked_attn_kernel<false><<<grid, 256, 0, stream>>>(q, k, v, csz, sidx, nullptr, out);
    }
}

// Round 15
// 148.983 us; speedup vs baseline: 2.0769x; 2.0769x over previous
//
#include <hip/hip_runtime.h>

typedef _Float16 f16x8 __attribute__((ext_vector_type(8)));
typedef _Float16 f16x4 __attribute__((ext_vector_type(4)));
typedef _Float16 f16x2 __attribute__((ext_vector_type(2)));
typedef float    f32x4 __attribute__((ext_vector_type(4)));

#define B_N    4
#define L_TOT  4096
#define H_N    16
#define DH     64
#define HALF_D 32
#define QT     64
#define KT     64
#define LDSP   72          // fallback kernel pad

#define LOG2_BASE 13.287712379549449f   // log2(10000)
#define LOG2E     1.4426950408889634f

#define TAB_BYTES  ((size_t)L_TOT * 64 * sizeof(float))          // 1 MB
#define IMG_BYTES  ((size_t)B_N * H_N * 64 * 8192)               // 32 MB per image

// ---------------- RoPE cos/sin table: tab[l][0..31]=cos, [32..63]=sin ----------------
__global__ void rope_table_kernel(const int* __restrict__ sidx, float* __restrict__ tab) {
    int idx = blockIdx.x * 256 + (int)threadIdx.x;
    if (idx >= L_TOT * HALF_D) return;
    int l = idx >> 5;
    int j = idx & 31;
    float invf = exp2f(-(float)j * (LOG2_BASE / (float)HALF_D));
    float ang = (float)(sidx[0] + l) * invf;
    float s, c;
    sincosf(ang, &s, &c);
    tab[l * 64 + j] = c;
    tab[l * 64 + HALF_D + j] = s;
}

// ---------------- fused prep: K (RoPE'd) + V^T, both XOR-swizzled f16 image tiles ----------------
// tile layout: [row 0..63][chunk 0..7 of 16B], stored chunk' = chunk ^ (row&7)
__global__ __launch_bounds__(256)
void prep_kernel(const float* __restrict__ k, const float* __restrict__ v,
                 const float* __restrict__ tab,
                 unsigned char* __restrict__ kimg, unsigned char* __restrict__ vimg)
{
    __shared__ float Vs[64][65];
    int bid = (int)blockIdx.x;
    int t = (int)threadIdx.x;

    if (bid < 4096) {
        // ---- K: each task handles chunk pair (c, c+4) of one row -> reads k exactly once ----
        int task = bid * 256 + t;              // B*H*L*4 tasks
        int c = task & 3;
        int rowid = task >> 2;
        int l = rowid & (L_TOT - 1);
        int bh = rowid >> 12;
        int b = bh >> 4, h = bh & 15;
        int d0 = c * 8;                        // 0,8,16,24
        const float* src = k + (((size_t)b * L_TOT + l) * H_N + h) * (size_t)DH;
        f32x4 x1a = *(const f32x4*)(src + d0);
        f32x4 x1b = *(const f32x4*)(src + d0 + 4);
        f32x4 x2a = *(const f32x4*)(src + d0 + HALF_D);
        f32x4 x2b = *(const f32x4*)(src + d0 + HALF_D + 4);
        const float* tr = tab + (size_t)l * 64 + d0;
        f32x4 ca = *(const f32x4*)(tr);
        f32x4 cb = *(const f32x4*)(tr + 4);
        f32x4 sa = *(const f32x4*)(tr + HALF_D);
        f32x4 sb = *(const f32x4*)(tr + HALF_D + 4);
        f16x8 olo, ohi;
#pragma unroll
        for (int j = 0; j < 4; ++j) {
            olo[j]     = (_Float16)(x1a[j] * ca[j] - x2a[j] * sa[j]);
            olo[j + 4] = (_Float16)(x1b[j] * cb[j] - x2b[j] * sb[j]);
            ohi[j]     = (_Float16)(x1a[j] * sa[j] + x2a[j] * ca[j]);
            ohi[j + 4] = (_Float16)(x1b[j] * sb[j] + x2b[j] * cb[j]);
        }
        size_t tile = (size_t)bh * 64 + (l >> 6);
        unsigned char* dst = kimg + tile * 8192 + (size_t)(l & 63) * 128;
        int sw = (c ^ (l & 7)) << 4;
        *(f16x8*)(dst + sw)        = olo;      // chunk c   (d = 8c..8c+7)
        *(f16x8*)(dst + (sw ^ 64)) = ohi;      // chunk c+4 (d+32)
    } else {
        // ---- V: transpose one 64x64 tile, store swizzled ----
        int vb = bid - 4096;                   // b*H*64 + h*64 + tile
        int tile = vb & 63;
        int h = (vb >> 6) & 15;
        int b = vb >> 10;
        int kbase = tile * 64;
        int row = t >> 2, cb = t & 3;
        const float* src = v + (((size_t)b * L_TOT + kbase + row) * H_N + h) * (size_t)DH + cb * 16;
        f32x4 a0 = *(const f32x4*)(src);
        f32x4 a1 = *(const f32x4*)(src + 4);
        f32x4 a2 = *(const f32x4*)(src + 8);
        f32x4 a3 = *(const f32x4*)(src + 12);
#pragma unroll
        for (int j = 0; j < 4; ++j) {
            Vs[row][cb * 16 + j]      = a0[j];
            Vs[row][cb * 16 + 4 + j]  = a1[j];
            Vs[row][cb * 16 + 8 + j]  = a2[j];
            Vs[row][cb * 16 + 12 + j] = a3[j];
        }
        __syncthreads();
        size_t tbase = ((size_t)(b * 16 + h) * 64 + tile) * 8192;
#pragma unroll
        for (int e = 0; e < 2; ++e) {
            int task = e * 256 + t;            // dv x chunk
            int dv = task >> 3, c = task & 7;
            f16x8 o;
#pragma unroll
            for (int j = 0; j < 8; ++j) o[j] = (_Float16)Vs[8 * c + j][dv];
            *(f16x8*)(vimg + tbase + (size_t)dv * 128 + ((c ^ (dv & 7)) << 4)) = o;
        }
    }
}

// ---------------- async global->LDS 16B ----------------
__device__ __forceinline__ void gl_lds16(const void* g, void* lds) {
    __builtin_amdgcn_global_load_lds(
        (const __attribute__((address_space(1))) unsigned int*)g,
        (__attribute__((address_space(3))) unsigned int*)lds, 16, 0, 0);
}

// ---------------- main fused attention: round-3 structure + round-5 VALU diet ----------------
// LDS: [K buf0 8K | K buf1 8K | V buf0 8K | V buf1 8K | P 4x2K] = 40 KB -> 4 blocks/CU
__global__ __launch_bounds__(256, 4)
void attn_main_kernel(const float* __restrict__ q, const int* __restrict__ csz,
                      const float* __restrict__ tab,
                      const unsigned char* __restrict__ kimg,
                      const unsigned char* __restrict__ vimg,
                      float* __restrict__ out) {
    __shared__ __align__(16) unsigned char smem[40960];

    const int tid  = (int)threadIdx.x;
    const int lane = tid & 63;
    const int w    = tid >> 6;         // wave 0..3, owns q rows [16w,16w+16)
    const int cl   = lane & 15;
    const int g    = lane >> 4;
    const int e7   = cl & 7;

    // XCD swizzle (bijective, 4096 % 8 == 0)
    const int bid0  = (int)blockIdx.x;
    const int wg    = (bid0 & 7) * 512 + (bid0 >> 3);
    const int qx    = wg & 63;
    const int h     = (wg >> 6) & 15;
    const int b     = wg >> 10;

    const int C   = csz[0];
    const int tpc = C >> 6;
    const int qtile = qx ^ ((tpc - 1) & 63);     // heavy-first within chunk
    const int kb0 = (qtile / tpc) * tpc;

    // ---- Q fragment (rows by cl), RoPE via tab, log2e folded in ----
    const int qr = qtile * QT + w * 16 + cl;
    const float* qs = q + (((size_t)b * L_TOT + qr) * H_N + h) * (size_t)DH;
    f32x4 x1a = *(const f32x4*)(qs + 8 * g);
    f32x4 x1b = *(const f32x4*)(qs + 8 * g + 4);
    f32x4 x2a = *(const f32x4*)(qs + 8 * g + HALF_D);
    f32x4 x2b = *(const f32x4*)(qs + 8 * g + HALF_D + 4);
    const float* tr = tab + (size_t)qr * 64 + 8 * g;
    f32x4 ca = *(const f32x4*)(tr);
    f32x4 cb = *(const f32x4*)(tr + 4);
    f32x4 sa = *(const f32x4*)(tr + HALF_D);
    f32x4 sb = *(const f32x4*)(tr + HALF_D + 4);
    f16x8 qa0, qa1;
#pragma unroll
    for (int j = 0; j < 4; ++j) {
        qa0[j]     = (_Float16)((x1a[j] * ca[j] - x2a[j] * sa[j]) * LOG2E);
        qa0[j + 4] = (_Float16)((x1b[j] * cb[j] - x2b[j] * sb[j]) * LOG2E);
        qa1[j]     = (_Float16)((x1a[j] * sa[j] + x2a[j] * ca[j]) * LOG2E);
        qa1[j + 4] = (_Float16)((x1b[j] * sb[j] + x2b[j] * cb[j]) * LOG2E);
    }

    const unsigned char* ksrc = kimg + (size_t)(b * 16 + h) * 64 * 8192;
    const unsigned char* vsrc = vimg + (size_t)(b * 16 + h) * 64 * 8192;

    // XOR address algebra: second K=32 half = addr ^ 64; P chunk c = base ^ (c<<5)
    const int krd = cl * 128 + ((g ^ e7) << 4);
    const int pwb = cl * 128 + (((g >> 1) ^ e7) << 4) + (g & 1) * 8;
    char* Pw = (char*)(smem + 32768 + w * 2048);

    // accumulators: O^T[dv=16ct+4g+r][q=cl], softmax state in log2 domain
    f32x4 o[4] = {};
    float m = -3e38f, l = 0.f;

    // ---- prologue: stage K+V tile kb0 into buf 0 (256 thr: 2 x 16B each per image) ----
    {
        const unsigned char* gk = ksrc + (size_t)kb0 * 8192;
        const unsigned char* gv = vsrc + (size_t)kb0 * 8192;
        gl_lds16(gk + tid * 16,        smem + tid * 16);
        gl_lds16(gk + tid * 16 + 4096, smem + tid * 16 + 4096);
        gl_lds16(gv + tid * 16,        smem + 16384 + tid * 16);
        gl_lds16(gv + tid * 16 + 4096, smem + 16384 + tid * 16 + 4096);
    }

    int pb = 0;
    for (int kb = kb0; kb <= qtile; ++kb) {
        __syncthreads();   // compiler drains vmcnt before barrier: buf pb ready, pb^1 free

        const char* Kb = (const char*)(smem + pb * 8192);
        const char* Vb = (const char*)(smem + 16384 + pb * 8192);
        if (kb < qtile) {  // prefetch next K+V tile into other buffer
            const unsigned char* nk = ksrc + (size_t)(kb + 1) * 8192;
            const unsigned char* nv = vsrc + (size_t)(kb + 1) * 8192;
            unsigned char* lk = smem + (pb ^ 1) * 8192;
            unsigned char* lv = smem + 16384 + (pb ^ 1) * 8192;
            gl_lds16(nk + tid * 16,        lk + tid * 16);
            gl_lds16(nk + tid * 16 + 4096, lk + tid * 16 + 4096);
            gl_lds16(nv + tid * 16,        lv + tid * 16);
            gl_lds16(nv + tid * 16 + 4096, lv + tid * 16 + 4096);
        }

        // ---- swapped QK^T: sc[ct][r] = S[q=cl][k=16ct+4g+r] (log2 domain) ----
        f32x4 sc[4];
        __builtin_amdgcn_s_setprio(1);
#pragma unroll
        for (int ct = 0; ct < 4; ++ct) {
            f16x8 kf0 = *(const f16x8*)(Kb + krd + ct * 2048);
            f16x8 kf1 = *(const f16x8*)(Kb + ((krd + ct * 2048) ^ 64));
            f32x4 z = {};
            z = __builtin_amdgcn_mfma_f32_16x16x32_f16(kf0, qa0, z, 0, 0, 0);
            sc[ct] = __builtin_amdgcn_mfma_f32_16x16x32_f16(kf1, qa1, z, 0, 0, 0);
        }
        __builtin_amdgcn_s_setprio(0);

        // ---- causal mask on diagonal tile ----
        if (kb == qtile) {
            const int qloc = w * 16 + cl;
#pragma unroll
            for (int ct = 0; ct < 4; ++ct)
#pragma unroll
                for (int r = 0; r < 4; ++r)
                    if (ct * 16 + 4 * g + r > qloc) sc[ct][r] = -3e38f;
        }

        // ---- online softmax (log2 domain), defer-max ----
        float mx = sc[0][0];
#pragma unroll
        for (int ct = 0; ct < 4; ++ct)
#pragma unroll
            for (int r = 0; r < 4; ++r) mx = fmaxf(mx, sc[ct][r]);
        mx = fmaxf(mx, __shfl_xor(mx, 16));
        mx = fmaxf(mx, __shfl_xor(mx, 32));
        if (__any(mx - m > 8.0f)) {
            float mn  = fmaxf(m, mx);
            float scl = exp2f(m - mn);
            m = mn;
            l *= scl;
#pragma unroll
            for (int ct = 0; ct < 4; ++ct)
#pragma unroll
                for (int r = 0; r < 4; ++r) o[ct][r] *= scl;
        }
        float ps = 0.f;
#pragma unroll
        for (int ct = 0; ct < 4; ++ct)
#pragma unroll
            for (int r = 0; r < 4; ++r) {
                float p = exp2f(sc[ct][r] - m);   // bounded by 2^8
                sc[ct][r] = p;
                ps += p;
            }
        ps += __shfl_xor(ps, 16);
        ps += __shfl_xor(ps, 32);
        l += ps;

        // ---- P -> per-wave swizzled image: 8 pkrtz + 4 ds_write_b64 ----
#pragma unroll
        for (int c = 0; c < 4; ++c) {
            f16x2 lo = __builtin_bit_cast(f16x2, __builtin_amdgcn_cvt_pkrtz(sc[c][0], sc[c][1]));
            f16x2 hi = __builtin_bit_cast(f16x2, __builtin_amdgcn_cvt_pkrtz(sc[c][2], sc[c][3]));
            f16x4 pv = __builtin_shufflevector(lo, hi, 0, 1, 2, 3);
            *(f16x4*)(Pw + (pwb ^ (c << 5))) = pv;
        }

        // ---- PV: O^T += V^T . P^T (V from LDS, validated access) ----
        f16x8 pa0 = *(const f16x8*)(Pw + krd);
        f16x8 pa1 = *(const f16x8*)(Pw + (krd ^ 64));
        __builtin_amdgcn_s_setprio(1);
#pragma unroll
        for (int ct = 0; ct < 4; ++ct) {
            f16x8 v0 = *(const f16x8*)(Vb + krd + ct * 2048);
            o[ct] = __builtin_amdgcn_mfma_f32_16x16x32_f16(v0, pa0, o[ct], 0, 0, 0);
        }
#pragma unroll
        for (int ct = 0; ct < 4; ++ct) {
            f16x8 v1 = *(const f16x8*)(Vb + ((krd + ct * 2048) ^ 64));
            o[ct] = __builtin_amdgcn_mfma_f32_16x16x32_f16(v1, pa1, o[ct], 0, 0, 0);
        }
        __builtin_amdgcn_s_setprio(0);

        pb ^= 1;
    }

    // ---- epilogue: transpose O^T through LDS, coalesced f32x4 stores ----
    __syncthreads();                       // all waves done with K/V/P before aliasing
    float* Ow = (float*)smem;              // [64][66] f32 = 16.9 KB
    float inv = 1.f / l;
#pragma unroll
    for (int ct = 0; ct < 4; ++ct)
#pragma unroll
        for (int r = 0; r < 4; ++r)
            Ow[(w * 16 + cl) * 66 + ct * 16 + 4 * g + r] = o[ct][r] * inv;
    __syncthreads();
    int row_l = tid >> 2;
    int cb4 = (tid & 3) * 16;
    const float* orow = Ow + row_l * 66 + cb4;
    float* gdst = out + (((size_t)b * L_TOT + qtile * QT + row_l) * H_N + h) * (size_t)DH + cb4;
#pragma unroll
    for (int jj = 0; jj < 4; ++jj) {
        f32x4 val;
#pragma unroll
        for (int x = 0; x < 4; ++x) val[x] = orow[4 * jj + x];
        *(f32x4*)(gdst + 4 * jj) = val;
    }
}

// ================= fallback (round-2 kernel, unchanged) =================
__device__ __forceinline__ void rope_cs_inline(float pos, int d, float* cc, float* ss) {
    float invf = exp2f(-(float)d * (LOG2_BASE / (float)HALF_D));
    float s, c;
    sincosf(pos * invf, &s, &c);
    *cc = c;
    *ss = s;
}

template<bool TAB>
__global__ __launch_bounds__(256)
void chunked_attn_kernel(const float* __restrict__ q, const float* __restrict__ k,
                         const float* __restrict__ v, const int* __restrict__ csz,
                         const int* __restrict__ sidx, const float* __restrict__ tab,
                         float* __restrict__ out)
{
    __shared__ _Float16 Ks[KT][LDSP];
    __shared__ _Float16 Vt[DH][LDSP];
    __shared__ _Float16 Ps[4][16][LDSP];

    const int tid  = (int)threadIdx.x;
    const int lane = tid & 63;
    const int w    = tid >> 6;
    const int cl   = lane & 15;
    const int g    = lane >> 4;

    const int bid   = (int)blockIdx.x;
    const int qtile = bid & (L_TOT / QT - 1);
    const int h     = (bid >> 6) & (H_N - 1);
    const int b     = bid >> 10;

    const int C   = csz[0];
    const int S0  = sidx[0];
    const int tpc = C / KT;
    const int kb0 = (qtile / tpc) * tpc;

    const int qrow = qtile * QT + w * 16 + cl;
    const size_t qoff = (((size_t)b * L_TOT + qrow) * H_N + h) * (size_t)DH;
    f32x4 x1a = *(const f32x4*)(q + qoff + 8 * g);
    f32x4 x1b = *(const f32x4*)(q + qoff + 8 * g + 4);
    f32x4 x2a = *(const f32x4*)(q + qoff + 8 * g + HALF_D);
    f32x4 x2b = *(const f32x4*)(q + qoff + 8 * g + HALF_D + 4);
    f32x4 ca, cb, sa, sb;
    if (TAB) {
        const float* tr = tab + (size_t)qrow * 64 + 8 * g;
        ca = *(const f32x4*)(tr);
        cb = *(const f32x4*)(tr + 4);
        sa = *(const f32x4*)(tr + HALF_D);
        sb = *(const f32x4*)(tr + HALF_D + 4);
    } else {
        float pos = (float)(S0 + qrow);
#pragma unroll
        for (int j = 0; j < 4; ++j) {
            float c0, s0, c1, s1;
            rope_cs_inline(pos, 8 * g + j,     &c0, &s0);
            rope_cs_inline(pos, 8 * g + 4 + j, &c1, &s1);
            ca[j] = c0; sa[j] = s0;
            cb[j] = c1; sb[j] = s1;
        }
    }
    f16x8 qa0, qa1;
#pragma unroll
    for (int j = 0; j < 4; ++j) {
        qa0[j]     = (_Float16)(x1a[j] * ca[j] - x2a[j] * sa[j]);
        qa0[j + 4] = (_Float16)(x1b[j] * cb[j] - x2b[j] * sb[j]);
        qa1[j]     = (_Float16)(x1a[j] * sa[j] + x2a[j] * ca[j]);
        qa1[j + 4] = (_Float16)(x1b[j] * sb[j] + x2b[j] * cb[j]);
    }

    f32x4 o[4] = {};
    float m_r[4], l_r[4];
#pragma unroll
    for (int r = 0; r < 4; ++r) { m_r[r] = -3e38f; l_r[r] = 0.f; }

    for (int kb = kb0; kb <= qtile; ++kb) {
        __syncthreads();
        const int kbase = kb * KT;

#pragma unroll
        for (int e = 0; e < 2; ++e) {
            int task = e * 256 + tid;
            int kk = task >> 3;
            int dg = (task & 7) * 4;
            int grow = kbase + kk;
            size_t off = (((size_t)b * L_TOT + grow) * H_N + h) * (size_t)DH;
            f32x4 x1 = *(const f32x4*)(k + off + dg);
            f32x4 x2 = *(const f32x4*)(k + off + dg + HALF_D);
            f32x4 cc, ss;
            if (TAB) {
                const float* tr2 = tab + (size_t)grow * 64 + dg;
                cc = *(const f32x4*)(tr2);
                ss = *(const f32x4*)(tr2 + HALF_D);
            } else {
                float pos = (float)(S0 + grow);
#pragma unroll
                for (int j = 0; j < 4; ++j) {
                    float c0, s0;
                    rope_cs_inline(pos, dg + j, &c0, &s0);
                    cc[j] = c0; ss[j] = s0;
                }
            }
            f16x4 o1, o2;
#pragma unroll
            for (int j = 0; j < 4; ++j) {
                o1[j] = (_Float16)(x1[j] * cc[j] - x2[j] * ss[j]);
                o2[j] = (_Float16)(x1[j] * ss[j] + x2[j] * cc[j]);
            }
            *(f16x4*)&Ks[kk][dg]          = o1;
            *(f16x4*)&Ks[kk][dg + HALF_D] = o2;
        }

#pragma unroll
        for (int e = 0; e < 4; ++e) {
            int task = e * 256 + tid;
            int kk = task >> 4;
            int dq = (task & 15) * 4;
            int grow = kbase + kk;
            size_t off = (((size_t)b * L_TOT + grow) * H_N + h) * (size_t)DH + dq;
            f32x4 x = *(const f32x4*)(v + off);
#pragma unroll
            for (int i = 0; i < 4; ++i) Vt[dq + i][kk] = (_Float16)x[i];
        }
        __syncthreads();

        f32x4 sc[4];
#pragma unroll
        for (int ct = 0; ct < 4; ++ct) {
            f16x8 kf0 = *(const f16x8*)&Ks[ct * 16 + cl][8 * g];
            f16x8 kf1 = *(const f16x8*)&Ks[ct * 16 + cl][8 * g + HALF_D];
            f32x4 z = {};
            z = __builtin_amdgcn_mfma_f32_16x16x32_f16(qa0, kf0, z, 0, 0, 0);
            sc[ct] = __builtin_amdgcn_mfma_f32_16x16x32_f16(qa1, kf1, z, 0, 0, 0);
        }

        const int rowt = w * 16 + 4 * g;
        if (kb == qtile) {
#pragma unroll
            for (int ct = 0; ct < 4; ++ct)
#pragma unroll
                for (int r = 0; r < 4; ++r)
                    if (ct * 16 + cl > rowt + r) sc[ct][r] = -3e38f;
        }

        f32x4 mt;
#pragma unroll
        for (int r = 0; r < 4; ++r)
            mt[r] = fmaxf(fmaxf(sc[0][r], sc[1][r]), fmaxf(sc[2][r], sc[3][r]));
#pragma unroll
        for (int off = 1; off < 16; off <<= 1) {
#pragma unroll
            for (int r = 0; r < 4; ++r)
                mt[r] = fmaxf(mt[r], __shfl_xor(mt[r], off));
        }
        float scale_r[4];
#pragma unroll
        for (int r = 0; r < 4; ++r) {
            float mn = fmaxf(m_r[r], mt[r]);
            scale_r[r] = __expf(m_r[r] - mn);
            m_r[r] = mn;
        }
        f32x4 psum = {};
#pragma unroll
        for (int ct = 0; ct < 4; ++ct) {
#pragma unroll
            for (int r = 0; r < 4; ++r) {
                float pz = __expf(sc[ct][r] - m_r[r]);
                sc[ct][r] = pz;
                psum[r] += pz;
            }
        }
#pragma unroll
        for (int off = 1; off < 16; off <<= 1) {
#pragma unroll
            for (int r = 0; r < 4; ++r)
                psum[r] += __shfl_xor(psum[r], off);
        }
#pragma unroll
        for (int r = 0; r < 4; ++r) l_r[r] = l_r[r] * scale_r[r] + psum[r];
#pragma unroll
        for (int ct = 0; ct < 4; ++ct)
#pragma unroll
            for (int r = 0; r < 4; ++r) o[ct][r] *= scale_r[r];

#pragma unroll
        for (int ct = 0; ct < 4; ++ct)
#pragma unroll
            for (int r = 0; r < 4; ++r)
                Ps[w][4 * g + r][ct * 16 + cl] = (_Float16)sc[ct][r];

#pragma unroll
        for (int st = 0; st < 2; ++st) {
            f16x8 pa = *(const f16x8*)&Ps[w][cl][8 * g + 32 * st];
#pragma unroll
            for (int ct = 0; ct < 4; ++ct) {
                f16x8 vb = *(const f16x8*)&Vt[ct * 16 + cl][8 * g + 32 * st];
                o[ct] = __builtin_amdgcn_mfma_f32_16x16x32_f16(pa, vb, o[ct], 0, 0, 0);
            }
        }
    }

#pragma unroll
    for (int ct = 0; ct < 4; ++ct) {
#pragma unroll
        for (int r = 0; r < 4; ++r) {
            int row = qtile * QT + w * 16 + 4 * g + r;
            float val = o[ct][r] / l_r[r];
            out[(((size_t)b * L_TOT + row) * H_N + h) * (size_t)DH + ct * 16 + cl] = val;
        }
    }
}

extern "C" void kernel_launch(void* const* d_in, const int* in_sizes, int n_in,
                              void* d_out, int out_size, void* d_ws, size_t ws_size,
                              hipStream_t stream) {
    const float* q  = (const float*)d_in[0];
    const float* k  = (const float*)d_in[1];
    const float* v  = (const float*)d_in[2];
    const int* csz  = (const int*)d_in[3];
    const int* sidx = (const int*)d_in[4];
    float* out = (float*)d_out;

    const size_t TOTAL = TAB_BYTES + 2 * IMG_BYTES;   // ~66 MB
    const int grid = B_N * H_N * (L_TOT / QT);        // 4096

    if (ws_size >= TOTAL) {
        float* tab = (float*)d_ws;
        unsigned char* kimg = (unsigned char*)d_ws + TAB_BYTES;
        unsigned char* vimg = kimg + IMG_BYTES;
        rope_table_kernel<<<(L_TOT * HALF_D + 255) / 256, 256, 0, stream>>>(sidx, tab);
        prep_kernel<<<8192, 256, 0, stream>>>(k, v, tab, kimg, vimg);
        attn_main_kernel<<<grid, 256, 0, stream>>>(q, csz, tab, kimg, vimg, out);
    } else if (ws_size >= TAB_BYTES) {
        float* tab = (float*)d_ws;
        rope_table_kernel<<<(L_TOT * HALF_D + 255) / 256, 256, 0, stream>>>(sidx, tab);
        chunked_attn_kernel<true><<<grid, 256, 0, stream>>>(q, k, v, csz, sidx, tab, out);
    } else {
        chunked_attn_kernel<false><<<grid, 256, 0, stream>>>(q, k, v, csz, sidx, nullptr, out);
    }
}

// Round 16
// 145.694 us; speedup vs baseline: 2.1238x; 1.0226x over previous
//
#include <hip/hip_runtime.h>

typedef _Float16 f16x8 __attribute__((ext_vector_type(8)));
typedef _Float16 f16x4 __attribute__((ext_vector_type(4)));
typedef _Float16 f16x2 __attribute__((ext_vector_type(2)));
typedef float    f32x4 __attribute__((ext_vector_type(4)));

#define B_N    4
#define L_TOT  4096
#define H_N    16
#define DH     64
#define HALF_D 32
#define QT     64
#define KT     64
#define LDSP   72          // fallback kernel pad

#define LOG2_BASE 13.287712379549449f   // log2(10000)
#define LOG2E     1.4426950408889634f

#define TAB_BYTES  ((size_t)L_TOT * 64 * sizeof(float))          // 1 MB
#define IMG_BYTES  ((size_t)B_N * H_N * 64 * 8192)               // 32 MB per image

// ---------------- RoPE cos/sin table: tab[l][0..31]=cos, [32..63]=sin ----------------
__global__ void rope_table_kernel(const int* __restrict__ sidx, float* __restrict__ tab) {
    int idx = blockIdx.x * 256 + (int)threadIdx.x;
    if (idx >= L_TOT * HALF_D) return;
    int l = idx >> 5;
    int j = idx & 31;
    float invf = exp2f(-(float)j * (LOG2_BASE / (float)HALF_D));
    float ang = (float)(sidx[0] + l) * invf;
    float s, c;
    sincosf(ang, &s, &c);
    tab[l * 64 + j] = c;
    tab[l * 64 + HALF_D + j] = s;
}

// ---------------- fused prep: K (RoPE'd) + V^T, both XOR-swizzled f16 image tiles ----------------
// tile layout: [row 0..63][chunk 0..7 of 16B], stored chunk' = chunk ^ (row&7)
__global__ __launch_bounds__(256)
void prep_kernel(const float* __restrict__ k, const float* __restrict__ v,
                 const float* __restrict__ tab,
                 unsigned char* __restrict__ kimg, unsigned char* __restrict__ vimg)
{
    __shared__ float Vs[64][65];
    int bid = (int)blockIdx.x;
    int t = (int)threadIdx.x;

    if (bid < 4096) {
        // ---- K: each task handles chunk pair (c, c+4) of one row -> reads k exactly once ----
        int task = bid * 256 + t;              // B*H*L*4 tasks
        int c = task & 3;
        int rowid = task >> 2;
        int l = rowid & (L_TOT - 1);
        int bh = rowid >> 12;
        int b = bh >> 4, h = bh & 15;
        int d0 = c * 8;                        // 0,8,16,24
        const float* src = k + (((size_t)b * L_TOT + l) * H_N + h) * (size_t)DH;
        f32x4 x1a = *(const f32x4*)(src + d0);
        f32x4 x1b = *(const f32x4*)(src + d0 + 4);
        f32x4 x2a = *(const f32x4*)(src + d0 + HALF_D);
        f32x4 x2b = *(const f32x4*)(src + d0 + HALF_D + 4);
        const float* tr = tab + (size_t)l * 64 + d0;
        f32x4 ca = *(const f32x4*)(tr);
        f32x4 cb = *(const f32x4*)(tr + 4);
        f32x4 sa = *(const f32x4*)(tr + HALF_D);
        f32x4 sb = *(const f32x4*)(tr + HALF_D + 4);
        f16x8 olo, ohi;
#pragma unroll
        for (int j = 0; j < 4; ++j) {
            olo[j]     = (_Float16)(x1a[j] * ca[j] - x2a[j] * sa[j]);
            olo[j + 4] = (_Float16)(x1b[j] * cb[j] - x2b[j] * sb[j]);
            ohi[j]     = (_Float16)(x1a[j] * sa[j] + x2a[j] * ca[j]);
            ohi[j + 4] = (_Float16)(x1b[j] * sb[j] + x2b[j] * cb[j]);
        }
        size_t tile = (size_t)bh * 64 + (l >> 6);
        unsigned char* dst = kimg + tile * 8192 + (size_t)(l & 63) * 128;
        int sw = (c ^ (l & 7)) << 4;
        *(f16x8*)(dst + sw)        = olo;      // chunk c   (d = 8c..8c+7)
        *(f16x8*)(dst + (sw ^ 64)) = ohi;      // chunk c+4 (d+32)
    } else {
        // ---- V: transpose one 64x64 tile, store swizzled ----
        int vb = bid - 4096;                   // b*H*64 + h*64 + tile
        int tile = vb & 63;
        int h = (vb >> 6) & 15;
        int b = vb >> 10;
        int kbase = tile * 64;
        int row = t >> 2, cb = t & 3;
        const float* src = v + (((size_t)b * L_TOT + kbase + row) * H_N + h) * (size_t)DH + cb * 16;
        f32x4 a0 = *(const f32x4*)(src);
        f32x4 a1 = *(const f32x4*)(src + 4);
        f32x4 a2 = *(const f32x4*)(src + 8);
        f32x4 a3 = *(const f32x4*)(src + 12);
#pragma unroll
        for (int j = 0; j < 4; ++j) {
            Vs[row][cb * 16 + j]      = a0[j];
            Vs[row][cb * 16 + 4 + j]  = a1[j];
            Vs[row][cb * 16 + 8 + j]  = a2[j];
            Vs[row][cb * 16 + 12 + j] = a3[j];
        }
        __syncthreads();
        size_t tbase = ((size_t)(b * 16 + h) * 64 + tile) * 8192;
#pragma unroll
        for (int e = 0; e < 2; ++e) {
            int task = e * 256 + t;            // dv x chunk
            int dv = task >> 3, c = task & 7;
            f16x8 o;
#pragma unroll
            for (int j = 0; j < 8; ++j) o[j] = (_Float16)Vs[8 * c + j][dv];
            *(f16x8*)(vimg + tbase + (size_t)dv * 128 + ((c ^ (dv & 7)) << 4)) = o;
        }
    }
}

// ---------------- async global->LDS 16B ----------------
__device__ __forceinline__ void gl_lds16(const void* g, void* lds) {
    __builtin_amdgcn_global_load_lds(
        (const __attribute__((address_space(1))) unsigned int*)g,
        (__attribute__((address_space(3))) unsigned int*)lds, 16, 0, 0);
}

// ---------------- main fused attention: round-7 structure, no setprio, direct-store epilogue ----------------
// LDS: [K buf0 8K | K buf1 8K | V buf0 8K | V buf1 8K | P 4x2K] = 40 KB -> 4 blocks/CU
__global__ __launch_bounds__(256, 4)
void attn_main_kernel(const float* __restrict__ q, const int* __restrict__ csz,
                      const float* __restrict__ tab,
                      const unsigned char* __restrict__ kimg,
                      const unsigned char* __restrict__ vimg,
                      float* __restrict__ out) {
    __shared__ __align__(16) unsigned char smem[40960];

    const int tid  = (int)threadIdx.x;
    const int lane = tid & 63;
    const int w    = tid >> 6;         // wave 0..3, owns q rows [16w,16w+16)
    const int cl   = lane & 15;
    const int g    = lane >> 4;
    const int e7   = cl & 7;

    // XCD swizzle (bijective, 4096 % 8 == 0)
    const int bid0  = (int)blockIdx.x;
    const int wg    = (bid0 & 7) * 512 + (bid0 >> 3);
    const int qx    = wg & 63;
    const int h     = (wg >> 6) & 15;
    const int b     = wg >> 10;

    const int C   = csz[0];
    const int tpc = C >> 6;
    const int qtile = qx ^ ((tpc - 1) & 63);     // heavy-first within chunk
    const int kb0 = (qtile / tpc) * tpc;

    // ---- Q fragment (rows by cl), RoPE via tab, log2e folded in ----
    const int qr = qtile * QT + w * 16 + cl;
    const float* qs = q + (((size_t)b * L_TOT + qr) * H_N + h) * (size_t)DH;
    f32x4 x1a = *(const f32x4*)(qs + 8 * g);
    f32x4 x1b = *(const f32x4*)(qs + 8 * g + 4);
    f32x4 x2a = *(const f32x4*)(qs + 8 * g + HALF_D);
    f32x4 x2b = *(const f32x4*)(qs + 8 * g + HALF_D + 4);
    const float* tr = tab + (size_t)qr * 64 + 8 * g;
    f32x4 ca = *(const f32x4*)(tr);
    f32x4 cb = *(const f32x4*)(tr + 4);
    f32x4 sa = *(const f32x4*)(tr + HALF_D);
    f32x4 sb = *(const f32x4*)(tr + HALF_D + 4);
    f16x8 qa0, qa1;
#pragma unroll
    for (int j = 0; j < 4; ++j) {
        qa0[j]     = (_Float16)((x1a[j] * ca[j] - x2a[j] * sa[j]) * LOG2E);
        qa0[j + 4] = (_Float16)((x1b[j] * cb[j] - x2b[j] * sb[j]) * LOG2E);
        qa1[j]     = (_Float16)((x1a[j] * sa[j] + x2a[j] * ca[j]) * LOG2E);
        qa1[j + 4] = (_Float16)((x1b[j] * sb[j] + x2b[j] * cb[j]) * LOG2E);
    }

    const unsigned char* ksrc = kimg + (size_t)(b * 16 + h) * 64 * 8192;
    const unsigned char* vsrc = vimg + (size_t)(b * 16 + h) * 64 * 8192;

    // XOR address algebra: second K=32 half = addr ^ 64; P chunk c = base ^ (c<<5)
    const int krd = cl * 128 + ((g ^ e7) << 4);
    const int pwb = cl * 128 + (((g >> 1) ^ e7) << 4) + (g & 1) * 8;
    char* Pw = (char*)(smem + 32768 + w * 2048);

    // accumulators: O^T[dv=16ct+4g+r][q=cl], softmax state in log2 domain
    f32x4 o[4] = {};
    float m = -3e38f, l = 0.f;

    // ---- prologue: stage K+V tile kb0 into buf 0 (256 thr: 2 x 16B each per image) ----
    {
        const unsigned char* gk = ksrc + (size_t)kb0 * 8192;
        const unsigned char* gv = vsrc + (size_t)kb0 * 8192;
        gl_lds16(gk + tid * 16,        smem + tid * 16);
        gl_lds16(gk + tid * 16 + 4096, smem + tid * 16 + 4096);
        gl_lds16(gv + tid * 16,        smem + 16384 + tid * 16);
        gl_lds16(gv + tid * 16 + 4096, smem + 16384 + tid * 16 + 4096);
    }

    int pb = 0;
    for (int kb = kb0; kb <= qtile; ++kb) {
        __syncthreads();   // compiler drains vmcnt before barrier: buf pb ready, pb^1 free

        const char* Kb = (const char*)(smem + pb * 8192);
        const char* Vb = (const char*)(smem + 16384 + pb * 8192);
        if (kb < qtile) {  // prefetch next K+V tile into other buffer
            const unsigned char* nk = ksrc + (size_t)(kb + 1) * 8192;
            const unsigned char* nv = vsrc + (size_t)(kb + 1) * 8192;
            unsigned char* lk = smem + (pb ^ 1) * 8192;
            unsigned char* lv = smem + 16384 + (pb ^ 1) * 8192;
            gl_lds16(nk + tid * 16,        lk + tid * 16);
            gl_lds16(nk + tid * 16 + 4096, lk + tid * 16 + 4096);
            gl_lds16(nv + tid * 16,        lv + tid * 16);
            gl_lds16(nv + tid * 16 + 4096, lv + tid * 16 + 4096);
        }

        // ---- swapped QK^T: sc[ct][r] = S[q=cl][k=16ct+4g+r] (log2 domain) ----
        f32x4 sc[4];
#pragma unroll
        for (int ct = 0; ct < 4; ++ct) {
            f16x8 kf0 = *(const f16x8*)(Kb + krd + ct * 2048);
            f16x8 kf1 = *(const f16x8*)(Kb + ((krd + ct * 2048) ^ 64));
            f32x4 z = {};
            z = __builtin_amdgcn_mfma_f32_16x16x32_f16(kf0, qa0, z, 0, 0, 0);
            sc[ct] = __builtin_amdgcn_mfma_f32_16x16x32_f16(kf1, qa1, z, 0, 0, 0);
        }

        // ---- causal mask on diagonal tile ----
        if (kb == qtile) {
            const int qloc = w * 16 + cl;
#pragma unroll
            for (int ct = 0; ct < 4; ++ct)
#pragma unroll
                for (int r = 0; r < 4; ++r)
                    if (ct * 16 + 4 * g + r > qloc) sc[ct][r] = -3e38f;
        }

        // ---- online softmax (log2 domain), defer-max ----
        float mx = sc[0][0];
#pragma unroll
        for (int ct = 0; ct < 4; ++ct)
#pragma unroll
            for (int r = 0; r < 4; ++r) mx = fmaxf(mx, sc[ct][r]);
        mx = fmaxf(mx, __shfl_xor(mx, 16));
        mx = fmaxf(mx, __shfl_xor(mx, 32));
        if (__any(mx - m > 8.0f)) {
            float mn  = fmaxf(m, mx);
            float scl = exp2f(m - mn);
            m = mn;
            l *= scl;
#pragma unroll
            for (int ct = 0; ct < 4; ++ct)
#pragma unroll
                for (int r = 0; r < 4; ++r) o[ct][r] *= scl;
        }
        float ps = 0.f;
#pragma unroll
        for (int ct = 0; ct < 4; ++ct)
#pragma unroll
            for (int r = 0; r < 4; ++r) {
                float p = exp2f(sc[ct][r] - m);   // bounded by 2^8
                sc[ct][r] = p;
                ps += p;
            }
        ps += __shfl_xor(ps, 16);
        ps += __shfl_xor(ps, 32);
        l += ps;

        // ---- P -> per-wave swizzled image: 8 pkrtz + 4 ds_write_b64 ----
#pragma unroll
        for (int c = 0; c < 4; ++c) {
            f16x2 lo = __builtin_bit_cast(f16x2, __builtin_amdgcn_cvt_pkrtz(sc[c][0], sc[c][1]));
            f16x2 hi = __builtin_bit_cast(f16x2, __builtin_amdgcn_cvt_pkrtz(sc[c][2], sc[c][3]));
            f16x4 pv = __builtin_shufflevector(lo, hi, 0, 1, 2, 3);
            *(f16x4*)(Pw + (pwb ^ (c << 5))) = pv;
        }

        // ---- PV: O^T += V^T . P^T (V from LDS, validated access) ----
        f16x8 pa0 = *(const f16x8*)(Pw + krd);
        f16x8 pa1 = *(const f16x8*)(Pw + (krd ^ 64));
#pragma unroll
        for (int ct = 0; ct < 4; ++ct) {
            f16x8 v0 = *(const f16x8*)(Vb + krd + ct * 2048);
            o[ct] = __builtin_amdgcn_mfma_f32_16x16x32_f16(v0, pa0, o[ct], 0, 0, 0);
        }
#pragma unroll
        for (int ct = 0; ct < 4; ++ct) {
            f16x8 v1 = *(const f16x8*)(Vb + ((krd + ct * 2048) ^ 64));
            o[ct] = __builtin_amdgcn_mfma_f32_16x16x32_f16(v1, pa1, o[ct], 0, 0, 0);
        }

        pb ^= 1;
    }

    // ---- epilogue: direct global stores (C/D map: lane holds dv = 16ct+4g+r, q = cl) ----
    // For fixed ct, r spans 4 contiguous dv at base 16ct+4g -> one f32x4 store per ct.
    float inv = 1.f / l;
    float* orow = out + (((size_t)b * L_TOT + qr) * H_N + h) * (size_t)DH;
#pragma unroll
    for (int ct = 0; ct < 4; ++ct) {
        f32x4 val;
#pragma unroll
        for (int r = 0; r < 4; ++r) val[r] = o[ct][r] * inv;
        *(f32x4*)(orow + ct * 16 + 4 * g) = val;
    }
}

// ================= fallback (round-2 kernel, unchanged) =================
__device__ __forceinline__ void rope_cs_inline(float pos, int d, float* cc, float* ss) {
    float invf = exp2f(-(float)d * (LOG2_BASE / (float)HALF_D));
    float s, c;
    sincosf(pos * invf, &s, &c);
    *cc = c;
    *ss = s;
}

template<bool TAB>
__global__ __launch_bounds__(256)
void chunked_attn_kernel(const float* __restrict__ q, const float* __restrict__ k,
                         const float* __restrict__ v, const int* __restrict__ csz,
                         const int* __restrict__ sidx, const float* __restrict__ tab,
                         float* __restrict__ out)
{
    __shared__ _Float16 Ks[KT][LDSP];
    __shared__ _Float16 Vt[DH][LDSP];
    __shared__ _Float16 Ps[4][16][LDSP];

    const int tid  = (int)threadIdx.x;
    const int lane = tid & 63;
    const int w    = tid >> 6;
    const int cl   = lane & 15;
    const int g    = lane >> 4;

    const int bid   = (int)blockIdx.x;
    const int qtile = bid & (L_TOT / QT - 1);
    const int h     = (bid >> 6) & (H_N - 1);
    const int b     = bid >> 10;

    const int C   = csz[0];
    const int S0  = sidx[0];
    const int tpc = C / KT;
    const int kb0 = (qtile / tpc) * tpc;

    const int qrow = qtile * QT + w * 16 + cl;
    const size_t qoff = (((size_t)b * L_TOT + qrow) * H_N + h) * (size_t)DH;
    f32x4 x1a = *(const f32x4*)(q + qoff + 8 * g);
    f32x4 x1b = *(const f32x4*)(q + qoff + 8 * g + 4);
    f32x4 x2a = *(const f32x4*)(q + qoff + 8 * g + HALF_D);
    f32x4 x2b = *(const f32x4*)(q + qoff + 8 * g + HALF_D + 4);
    f32x4 ca, cb, sa, sb;
    if (TAB) {
        const float* tr = tab + (size_t)qrow * 64 + 8 * g;
        ca = *(const f32x4*)(tr);
        cb = *(const f32x4*)(tr + 4);
        sa = *(const f32x4*)(tr + HALF_D);
        sb = *(const f32x4*)(tr + HALF_D + 4);
    } else {
        float pos = (float)(S0 + qrow);
#pragma unroll
        for (int j = 0; j < 4; ++j) {
            float c0, s0, c1, s1;
            rope_cs_inline(pos, 8 * g + j,     &c0, &s0);
            rope_cs_inline(pos, 8 * g + 4 + j, &c1, &s1);
            ca[j] = c0; sa[j] = s0;
            cb[j] = c1; sb[j] = s1;
        }
    }
    f16x8 qa0, qa1;
#pragma unroll
    for (int j = 0; j < 4; ++j) {
        qa0[j]     = (_Float16)(x1a[j] * ca[j] - x2a[j] * sa[j]);
        qa0[j + 4] = (_Float16)(x1b[j] * cb[j] - x2b[j] * sb[j]);
        qa1[j]     = (_Float16)(x1a[j] * sa[j] + x2a[j] * ca[j]);
        qa1[j + 4] = (_Float16)(x1b[j] * sb[j] + x2b[j] * cb[j]);
    }

    f32x4 o[4] = {};
    float m_r[4], l_r[4];
#pragma unroll
    for (int r = 0; r < 4; ++r) { m_r[r] = -3e38f; l_r[r] = 0.f; }

    for (int kb = kb0; kb <= qtile; ++kb) {
        __syncthreads();
        const int kbase = kb * KT;

#pragma unroll
        for (int e = 0; e < 2; ++e) {
            int task = e * 256 + tid;
            int kk = task >> 3;
            int dg = (task & 7) * 4;
            int grow = kbase + kk;
            size_t off = (((size_t)b * L_TOT + grow) * H_N + h) * (size_t)DH;
            f32x4 x1 = *(const f32x4*)(k + off + dg);
            f32x4 x2 = *(const f32x4*)(k + off + dg + HALF_D);
            f32x4 cc, ss;
            if (TAB) {
                const float* tr2 = tab + (size_t)grow * 64 + dg;
                cc = *(const f32x4*)(tr2);
                ss = *(const f32x4*)(tr2 + HALF_D);
            } else {
                float pos = (float)(S0 + grow);
#pragma unroll
                for (int j = 0; j < 4; ++j) {
                    float c0, s0;
                    rope_cs_inline(pos, dg + j, &c0, &s0);
                    cc[j] = c0; ss[j] = s0;
                }
            }
            f16x4 o1, o2;
#pragma unroll
            for (int j = 0; j < 4; ++j) {
                o1[j] = (_Float16)(x1[j] * cc[j] - x2[j] * ss[j]);
                o2[j] = (_Float16)(x1[j] * ss[j] + x2[j] * cc[j]);
            }
            *(f16x4*)&Ks[kk][dg]          = o1;
            *(f16x4*)&Ks[kk][dg + HALF_D] = o2;
        }

#pragma unroll
        for (int e = 0; e < 4; ++e) {
            int task = e * 256 + tid;
            int kk = task >> 4;
            int dq = (task & 15) * 4;
            int grow = kbase + kk;
            size_t off = (((size_t)b * L_TOT + grow) * H_N + h) * (size_t)DH + dq;
            f32x4 x = *(const f32x4*)(v + off);
#pragma unroll
            for (int i = 0; i < 4; ++i) Vt[dq + i][kk] = (_Float16)x[i];
        }
        __syncthreads();

        f32x4 sc[4];
#pragma unroll
        for (int ct = 0; ct < 4; ++ct) {
            f16x8 kf0 = *(const f16x8*)&Ks[ct * 16 + cl][8 * g];
            f16x8 kf1 = *(const f16x8*)&Ks[ct * 16 + cl][8 * g + HALF_D];
            f32x4 z = {};
            z = __builtin_amdgcn_mfma_f32_16x16x32_f16(qa0, kf0, z, 0, 0, 0);
            sc[ct] = __builtin_amdgcn_mfma_f32_16x16x32_f16(qa1, kf1, z, 0, 0, 0);
        }

        const int rowt = w * 16 + 4 * g;
        if (kb == qtile) {
#pragma unroll
            for (int ct = 0; ct < 4; ++ct)
#pragma unroll
                for (int r = 0; r < 4; ++r)
                    if (ct * 16 + cl > rowt + r) sc[ct][r] = -3e38f;
        }

        f32x4 mt;
#pragma unroll
        for (int r = 0; r < 4; ++r)
            mt[r] = fmaxf(fmaxf(sc[0][r], sc[1][r]), fmaxf(sc[2][r], sc[3][r]));
#pragma unroll
        for (int off = 1; off < 16; off <<= 1) {
#pragma unroll
            for (int r = 0; r < 4; ++r)
                mt[r] = fmaxf(mt[r], __shfl_xor(mt[r], off));
        }
        float scale_r[4];
#pragma unroll
        for (int r = 0; r < 4; ++r) {
            float mn = fmaxf(m_r[r], mt[r]);
            scale_r[r] = __expf(m_r[r] - mn);
            m_r[r] = mn;
        }
        f32x4 psum = {};
#pragma unroll
        for (int ct = 0; ct < 4; ++ct) {
#pragma unroll
            for (int r = 0; r < 4; ++r) {
                float pz = __expf(sc[ct][r] - m_r[r]);
                sc[ct][r] = pz;
                psum[r] += pz;
            }
        }
#pragma unroll
        for (int off = 1; off < 16; off <<= 1) {
#pragma unroll
            for (int r = 0; r < 4; ++r)
                psum[r] += __shfl_xor(psum[r], off);
        }
#pragma unroll
        for (int r = 0; r < 4; ++r) l_r[r] = l_r[r] * scale_r[r] + psum[r];
#pragma unroll
        for (int ct = 0; ct < 4; ++ct)
#pragma unroll
            for (int r = 0; r < 4; ++r) o[ct][r] *= scale_r[r];

#pragma unroll
        for (int ct = 0; ct < 4; ++ct)
#pragma unroll
            for (int r = 0; r < 4; ++r)
                Ps[w][4 * g + r][ct * 16 + cl] = (_Float16)sc[ct][r];

#pragma unroll
        for (int st = 0; st < 2; ++st) {
            f16x8 pa = *(const f16x8*)&Ps[w][cl][8 * g + 32 * st];
#pragma unroll
            for (int ct = 0; ct < 4; ++ct) {
                f16x8 vb = *(const f16x8*)&Vt[ct * 16 + cl][8 * g + 32 * st];
                o[ct] = __builtin_amdgcn_mfma_f32_16x16x32_f16(pa, vb, o[ct], 0, 0, 0);
            }
        }
    }

#pragma unroll
    for (int ct = 0; ct < 4; ++ct) {
#pragma unroll
        for (int r = 0; r < 4; ++r) {
            int row = qtile * QT + w * 16 + 4 * g + r;
            float val = o[ct][r] / l_r[r];
            out[(((size_t)b * L_TOT + row) * H_N + h) * (size_t)DH + ct * 16 + cl] = val;
        }
    }
}

extern "C" void kernel_launch(void* const* d_in, const int* in_sizes, int n_in,
                              void* d_out, int out_size, void* d_ws, size_t ws_size,
                              hipStream_t stream) {
    const float* q  = (const float*)d_in[0];
    const float* k  = (const float*)d_in[1];
    const float* v  = (const float*)d_in[2];
    const int* csz  = (const int*)d_in[3];
    const int* sidx = (const int*)d_in[4];
    float* out = (float*)d_out;

    const size_t TOTAL = TAB_BYTES + 2 * IMG_BYTES;   // ~66 MB
    const int grid = B_N * H_N * (L_TOT / QT);        // 4096

    if (ws_size >= TOTAL) {
        float* tab = (float*)d_ws;
        unsigned char* kimg = (unsigned char*)d_ws + TAB_BYTES;
        unsigned char* vimg = kimg + IMG_BYTES;
        rope_table_kernel<<<(L_TOT * HALF_D + 255) / 256, 256, 0, stream>>>(sidx, tab);
        prep_kernel<<<8192, 256, 0, stream>>>(k, v, tab, kimg, vimg);
        attn_main_kernel<<<grid, 256, 0, stream>>>(q, csz, tab, kimg, vimg, out);
    } else if (ws_size >= TAB_BYTES) {
        float* tab = (float*)d_ws;
        rope_table_kernel<<<(L_TOT * HALF_D + 255) / 256, 256, 0, stream>>>(sidx, tab);
        chunked_attn_kernel<true><<<grid, 256, 0, stream>>>(q, k, v, csz, sidx, tab, out);
    } else {
        chunked_attn_kernel<false><<<grid, 256, 0, stream>>>(q, k, v, csz, sidx, nullptr, out);
    }
}